// Round 1
// baseline (1150.070 us; speedup 1.0000x reference)
//
#include <hip/hip_runtime.h>
#include <hip/hip_bf16.h>
#include <stdint.h>

// Problem constants
#define B_   4
#define C_   256
#define H_   200
#define W_   336
#define OC_  512
#define HP_  202           // H + 2 (pad)
#define WP_  338           // W + 2 (pad)
#define M_   (B_*H_*W_)    // 268800 pixels = 2100 * 128 exactly
#define MTILES (M_/128)    // 2100
#define OUT0_ (M_*18)      // 4,838,400 cls elements
#define OUT_TOTAL_ (M_*54) // 14,515,200

// Workspace layout (bytes)
#define XP_ELEMS  ((size_t)B_*HP_*WP_*C_)   // 69,914,624
#define XP_BYTES  (XP_ELEMS*2)              // ~139.8 MB
#define W1T_ELEMS ((size_t)9*OC_*C_)        // 1,179,648
#define W1T_OFF   XP_BYTES
#define WHB_OFF   (W1T_OFF + W1T_ELEMS*2)

typedef unsigned short ushortT;
typedef __attribute__((ext_vector_type(8))) short bf16x8;   // 8 bf16 = 4 VGPR
typedef __attribute__((ext_vector_type(4))) float f32x4;

static __device__ __forceinline__ ushortT f2bf(float x) {
    union { float f; uint32_t u; } v; v.f = x;
    uint32_t r = v.u + 0x7fff + ((v.u >> 16) & 1);   // RNE
    return (ushortT)(r >> 16);
}

// ---------------------------------------------------------------------------
// Pre-pass 0: zero only the halo of the padded buffer.
__global__ __launch_bounds__(256) void zero_halo(ushortT* __restrict__ Xp) {
    int i = blockIdx.x * 256 + threadIdx.x;
    if (i >= 4 * 1076 * 32) return;
    int pix = i >> 5, ch = (i & 31) * 8;
    int b = pix / 1076, r = pix % 1076;
    int h, w;
    if (r < 338)      { h = 0;   w = r; }
    else if (r < 676) { h = 201; w = r - 338; }
    else { r -= 676; h = 1 + (r >> 1); w = (r & 1) ? 337 : 0; }
    size_t dst = (((size_t)b*HP_ + h)*WP_ + w)*C_ + ch;
    *(uint4*)(Xp + dst) = make_uint4(0, 0, 0, 0);
}

// Pre-pass 1: NCHW fp32 -> padded NHWC bf16 via LDS tile transpose.
__global__ __launch_bounds__(256) void pad_transpose(const float* __restrict__ X,
                                                     ushortT* __restrict__ Xp) {
    int bid = blockIdx.x;
    int wc = bid % 6; int bh = bid / 6;
    int h = bh % H_;  int b = bh / H_;
    int w0 = wc * 64;
    int t = threadIdx.x;
    __shared__ ushortT tile[64 * 65];

    for (int c0 = 0; c0 < C_; c0 += 64) {
        if (c0) __syncthreads();
        int col  = t & 63;
        int rowb = t >> 6;
        #pragma unroll
        for (int rr = 0; rr < 16; ++rr) {
            int row = rowb * 16 + rr;
            int w = w0 + col;
            float val = 0.f;
            if (w < W_)
                val = X[(((size_t)(b*C_ + c0 + row))*H_ + h)*W_ + w];
            tile[row*65 + col] = f2bf(val);
        }
        __syncthreads();
        int pixel = t >> 2;
        int csub  = (t & 3) * 16;
        int w = w0 + pixel;
        if (w < W_) {
            union { ushortT u[16]; uint4 q[2]; } vals;
            #pragma unroll
            for (int j = 0; j < 16; ++j)
                vals.u[j] = tile[(csub + j)*65 + pixel];
            size_t dst = (((size_t)b*HP_ + (h+1))*WP_ + (w+1))*C_ + c0 + csub;
            *(uint4*)(Xp + dst)     = vals.q[0];
            *(uint4*)(Xp + dst + 8) = vals.q[1];
        }
    }
}

// Pre-pass 2: W1 [oc][c][3][3] fp32 -> W1t [rs][oc][c] bf16
__global__ __launch_bounds__(256) void prep_w1(const float* __restrict__ W1,
                                               ushortT* __restrict__ W1t) {
    int t = blockIdx.x * 256 + threadIdx.x;
    if (t >= OC_*C_) return;
    const float* src = W1 + (size_t)t * 9;
    #pragma unroll
    for (int rs = 0; rs < 9; ++rs)
        W1t[(size_t)rs*OC_*C_ + t] = f2bf(src[rs]);
}

// Pre-pass 3: Wc[18][512], Wb[36][512] -> Whb[64][512] bf16 (rows 54..63 zero)
__global__ __launch_bounds__(256) void prep_whb(const float* __restrict__ Wc,
                                                const float* __restrict__ Wb,
                                                ushortT* __restrict__ Whb) {
    int t = blockIdx.x * 256 + threadIdx.x;
    if (t >= 64*512) return;
    int o = t >> 9, oc = t & 511;
    float v = 0.f;
    if (o < 18) v = Wc[o*512 + oc];
    else if (o < 54) v = Wb[(o-18)*512 + oc];
    Whb[t] = f2bf(v);
}

// ---------------------------------------------------------------------------
// Main fused kernel, v2: BM=128 x BN=512 (full oc per block), BK=64.
// 512 threads / 8 waves (2M x 4N), acc[4][8] per wave.
// LDS 160 KB: double-buffered A[128][64] + B[512][64] bf16.
//   layout (ushorts): [A buf0: 8192][A buf1: 8192][B buf0: 32768][B buf1: 32768]
// Counted-vmcnt pipeline (T3+T4): stage tile t+1 at top of tile t, raw
// s_barrier (no vmcnt drain), vmcnt(10) = the 10 just-issued loads allowed
// outstanding; vmcnt(0) only on the last tile. One lgkmcnt(0)+barrier at
// tile end = WAR fence for next iteration's staging.
// Head GEMM is complete per block (K=512) -> direct stores with bias:
// no atomics, no init_out pass.
#define CONV_GRID 2100

__global__ __launch_bounds__(512, 2) void conv_rpn(
    const ushortT* __restrict__ Xp, const ushortT* __restrict__ W1t,
    const float* __restrict__ b1,  const ushortT* __restrict__ Whb,
    const float* __restrict__ bc,  const float* __restrict__ bb,
    float* __restrict__ out)
{
    extern __shared__ ushortT smem[];

    const int tid  = threadIdx.x;
    const int wave = tid >> 6;          // 0..7
    const int lane = tid & 63;
    const int col  = lane & 15;
    const int quad = lane >> 4;
    const int c7   = col & 7;           // read de-swizzle key (row&7 == col&7)
    const int wm   = (wave >> 2) * 64;  // M offset of this wave (0 or 64)
    const int wn   = (wave & 3) * 128;  // N offset of this wave (0..384)

    // Bijective XCD swizzle for 2100 blocks over 8 XCDs (m204 variant).
    const int bid = blockIdx.x;
    const int xcd = bid & 7, ib = bid >> 3;
    const int mtile = (xcd < 4) ? (xcd*263 + ib) : (1052 + (xcd-4)*262 + ib);

    // Staging: lane (r8 = lane>>3) covers row r8 of each 8-row group; chunk
    // position lane&7 holds logical chunk (lane&7)^r8 (row-XOR swizzle).
    const int r8     = lane >> 3;
    const int lchunk = ((lane & 7) ^ r8) * 8;

    // A source addresses: 2 issues/wave/tile, rows wave*16 + i*8 + r8.
    size_t pixA[2];
    #pragma unroll
    for (int i = 0; i < 2; ++i) {
        int m = mtile*128 + wave*16 + i*8 + r8;
        int b = m / (H_*W_);
        int rem = m % (H_*W_);
        int hh = rem / W_;
        int ww = rem % W_;
        pixA[i] = (((size_t)b*HP_ + hh)*WP_ + ww)*C_ + lchunk;
    }
    // B source: 8 issues/wave/tile, oc rows wave*64 + i*8 + r8.
    const size_t bbase = ((size_t)(wave*64 + r8))*C_ + lchunk;

    f32x4 acc[4][8] = {};

    auto STAGE = [&](int t, int buf) {
        const int rs = t >> 2;
        const int cs = (t & 3) << 6;
        const int roff = ((rs/3)*WP_ + (rs%3)) * C_;
        const size_t wsrc = (size_t)rs*OC_*C_ + bbase + cs;
        ushortT* Ab = smem + buf*8192  + (wave*16)*64;
        ushortT* Bb = smem + 16384 + buf*32768 + (wave*64)*64;
        #pragma unroll
        for (int i = 0; i < 2; ++i)
            __builtin_amdgcn_global_load_lds(
                (const __attribute__((address_space(1))) uint32_t*)(Xp + pixA[i] + roff + cs),
                (__attribute__((address_space(3))) uint32_t*)(Ab + i*8*64), 16, 0, 0);
        #pragma unroll
        for (int i = 0; i < 8; ++i)
            __builtin_amdgcn_global_load_lds(
                (const __attribute__((address_space(1))) uint32_t*)(W1t + wsrc + (size_t)i*8*C_),
                (__attribute__((address_space(3))) uint32_t*)(Bb + i*8*64), 16, 0, 0);
    };

    STAGE(0, 0);

    #pragma unroll 1
    for (int t = 0; t < 36; ++t) {
        const int cur = t & 1;
        if (t < 35) {
            STAGE(t + 1, cur ^ 1);
            asm volatile("s_waitcnt vmcnt(10)" ::: "memory");
        } else {
            asm volatile("s_waitcnt vmcnt(0)" ::: "memory");
        }
        __builtin_amdgcn_sched_barrier(0);
        __builtin_amdgcn_s_barrier();
        __builtin_amdgcn_sched_barrier(0);

        const ushortT* Al = smem + cur*8192;
        const ushortT* Bl = smem + 16384 + cur*32768;
        #pragma unroll
        for (int kk = 0; kk < 2; ++kk) {
            const int pc = ((kk*4 + quad) ^ c7) * 8;
            bf16x8 af[4], bfr[8];
            #pragma unroll
            for (int mt = 0; mt < 4; ++mt)
                af[mt] = *(const bf16x8*)&Al[(wm + mt*16 + col)*64 + pc];
            #pragma unroll
            for (int nt = 0; nt < 8; ++nt)
                bfr[nt] = *(const bf16x8*)&Bl[(wn + nt*16 + col)*64 + pc];
            __builtin_amdgcn_s_setprio(1);
            #pragma unroll
            for (int mt = 0; mt < 4; ++mt)
                #pragma unroll
                for (int nt = 0; nt < 8; ++nt)
                    acc[mt][nt] = __builtin_amdgcn_mfma_f32_16x16x32_bf16(
                        af[mt], bfr[nt], acc[mt][nt], 0, 0, 0);
            __builtin_amdgcn_s_setprio(0);
        }
        asm volatile("s_waitcnt lgkmcnt(0)" ::: "memory");
        __builtin_amdgcn_sched_barrier(0);
        __builtin_amdgcn_s_barrier();
        __builtin_amdgcn_sched_barrier(0);
    }

    // ---- Epilogue: +b1, ReLU, feat -> Fsm[128][512] bf16 (reuses all LDS).
    // Swizzle: 16B-chunk (colc>>3) XOR (row&7), same involution on read.
    ushortT* Fsm = smem;
    float b1v[8];
    #pragma unroll
    for (int nt = 0; nt < 8; ++nt) b1v[nt] = b1[wn + nt*16 + col];
    #pragma unroll
    for (int mt = 0; mt < 4; ++mt)
        #pragma unroll
        for (int nt = 0; nt < 8; ++nt) {
            const float bv = b1v[nt];
            #pragma unroll
            for (int rg = 0; rg < 4; ++rg) {
                int row  = wm + mt*16 + quad*4 + rg;
                int colc = wn + nt*16 + col;
                float v = fmaxf(acc[mt][nt][rg] + bv, 0.f);
                int pos = (((colc >> 3) ^ (row & 7)) << 3) | (colc & 7);
                Fsm[row*512 + pos] = f2bf(v);
            }
        }
    __syncthreads();

    // ---- Head GEMM: M=128 pixels, N=64 (54 used), K=512 (complete).
    f32x4 hacc[4] = {};
    const int hrow = wave*16 + col;
    const int h7   = col & 7;     // hrow&7 == col&7
    const ushortT* Fr = Fsm + hrow*512;
    #pragma unroll
    for (int ks = 0; ks < 16; ++ks) {
        bf16x8 ah = *(const bf16x8*)&Fr[((ks*4 + quad) ^ h7) << 3];
        #pragma unroll
        for (int nt = 0; nt < 4; ++nt) {
            bf16x8 bh = *(const bf16x8*)&Whb[(nt*16 + col)*512 + ks*32 + quad*8];
            hacc[nt] = __builtin_amdgcn_mfma_f32_16x16x32_bf16(
                ah, bh, hacc[nt], 0, 0, 0);
        }
    }

    // ---- Direct stores with head bias (single writer per element).
    #pragma unroll
    for (int nt = 0; nt < 4; ++nt) {
        int o = nt*16 + col;
        float bias = (o < 18) ? bc[o] : (o < 54 ? bb[o - 18] : 0.f);
        #pragma unroll
        for (int rg = 0; rg < 4; ++rg) {
            size_t p = (size_t)mtile*128 + wave*16 + quad*4 + rg;
            float v = hacc[nt][rg] + bias;
            if (o < 18)      out[p*18 + o] = v;
            else if (o < 54) out[OUT0_ + p*36 + (o - 18)] = v;
        }
    }
}

// ---------------------------------------------------------------------------
extern "C" void kernel_launch(void* const* d_in, const int* in_sizes, int n_in,
                              void* d_out, int out_size, void* d_ws, size_t ws_size,
                              hipStream_t stream) {
    const float* X  = (const float*)d_in[0];
    const float* W1 = (const float*)d_in[1];
    const float* b1 = (const float*)d_in[2];
    const float* Wc = (const float*)d_in[3];
    const float* bc = (const float*)d_in[4];
    const float* Wb = (const float*)d_in[5];
    const float* bb = (const float*)d_in[6];
    float* out = (float*)d_out;

    ushortT* Xp  = (ushortT*)d_ws;
    ushortT* W1t = (ushortT*)((char*)d_ws + W1T_OFF);
    ushortT* Whb = (ushortT*)((char*)d_ws + WHB_OFF);

    static bool attr_set = false;
    if (!attr_set) {
        hipFuncSetAttribute((const void*)conv_rpn,
                            hipFuncAttributeMaxDynamicSharedMemorySize, 163840);
        attr_set = true;
    }

    zero_halo<<<(4*1076*32 + 255)/256, 256, 0, stream>>>(Xp);
    pad_transpose<<<B_*H_*6, 256, 0, stream>>>(X, Xp);
    prep_w1<<<(OC_*C_ + 255)/256, 256, 0, stream>>>(W1, W1t);
    prep_whb<<<(64*512 + 255)/256, 256, 0, stream>>>(Wc, Wb, Whb);
    conv_rpn<<<CONV_GRID, 512, 163840, stream>>>(Xp, W1t, b1, Whb, bc, bb, out);
}